// Round 4
// baseline (26608.356 us; speedup 1.0000x reference)
//
#include <hip/hip_runtime.h>

// ============================================================================
// 2-layer LSTM (B=256, T=1024, H=512, in=1) + linear head. fp32 in/out.
//
// R8 (from R7 @10.29ms): rebalance per-CU delivery pipes. R7 pipe model:
//  L0 CU: TCP 256KB/step (nh-wave pairs read IDENTICAL A streams, 2x dup)
//         = 1.7us; LDS 256KB = 0.85us; MFMA 0.53us.
//  L1 CU: LDS 512KB/step (4 waves read the SAME B sequence) = 1.7us;
//         TCP 256KB = 1.7us; MFMA 0.53us.
// Fix: 128-thread WGs, 2 waves, wave = 32-row half handling ALL gate groups:
//  L0: A dup gone -> TCP 128KB (0.85us), LDS 256KB (0.85), MFMA 1.07us.
//  L1: LDS halves -> 256KB (0.85us), TCP 1.7us, MFMA 1.07us.
// Sync structure FROZEN vs R7 (isolate the variable): slice-major transport
// + full-line coop stores (R7 win, -21%), per-slice flags stored after
// vmcnt-drained stores, lane-parallel polls, combined L0 pf/qf poll,
// L1 runahead (cached monotonic pf), epoch buffer_inv sc1, deferred head
// atomic. Math bit-identical (absmax 6.1e-5 expected).
// Predicted: dur -> 6-7.5ms, MfmaUtil ~20-25 if pipe-bound; dur flat =>
// sync-chain bound, R9 attacks flag topology.
// ============================================================================

typedef _Float16 f16;
typedef _Float16 f16x8 __attribute__((ext_vector_type(8)));
typedef float f32x4 __attribute__((ext_vector_type(4)));
typedef unsigned long long u64;

#define NB 256
#define NT_ 1024
#define NH 512
#define RING 16
#define SLOT (NB * NH)

__device__ __forceinline__ float sigm(float x)  { return 1.0f / (1.0f + __expf(-x)); }
__device__ __forceinline__ float tanhx(float x) { return 2.0f / (1.0f + __expf(-2.0f * x)) - 1.0f; }

// 8B agent-visible write-through store (verified R3/R4/R7 transport primitive)
__device__ __forceinline__ void st8(unsigned short* p, u64 v) {
  __hip_atomic_store((u64*)p, v, __ATOMIC_RELAXED, __HIP_MEMORY_SCOPE_AGENT);
}
__device__ __forceinline__ unsigned ldf(const unsigned* p) {
  return __hip_atomic_load(p, __ATOMIC_RELAXED, __HIP_MEMORY_SCOPE_AGENT);
}
// Poll until every lane's flag (per-lane address/threshold) passes. Returns
// the last value this lane read (for runahead caching — flags are monotonic).
__device__ __forceinline__ unsigned pollr(const unsigned* a, unsigned thr) {
  unsigned v;
  for (;;) {
    v = ldf(a);
    if (!~__ballot(v >= thr)) break;
    __builtin_amdgcn_s_sleep(2);
  }
  asm volatile("" ::: "memory");
  return v;
}

// ---------------------------------------------------------------------------
__global__ void prep_xT(const float* __restrict__ inp, float* __restrict__ xT) {
  int g = blockIdx.x * 256 + threadIdx.x;
  int t = g >> 8, b = g & 255;
  xT[t * NB + b] = inp[b * NT_ + t];
}

// ---------------------------------------------------------------------------
// fp32 -> fp16 weights in MFMA B-fragment order (verified R3; unchanged).
// L0 (Wh0): 16 slices x [nh<2][gate<4][kt<16][lane<64][j<8]; slice=65536 elems.
// L1 (Wx1, Wh1): 32 slices x [nh<2][jt<2][kt<16][lane<64][j<8]; slice=32768.
__global__ void prep_w(const float* __restrict__ Wh0,
                       const float* __restrict__ Wx1,
                       const float* __restrict__ Wh1,
                       f16* __restrict__ dst) {
  int g = blockIdx.x * 256 + threadIdx.x;   // 3 * 2^20 threads
  int mat = g >> 20;
  int r = g & 0xFFFFF;
  int j = r & 7, ln = (r >> 3) & 63, kt = (r >> 9) & 15;
  int cl = ln & 15, qd = ln >> 4;
  int k = kt * 32 + qd * 8 + j;
  size_t di; int gcol; const float* W;
  if (mat == 0) {
    int gt = (r >> 13) & 3, nh = (r >> 15) & 1, sl = (r >> 16) & 15;
    W = Wh0;
    gcol = gt * 512 + sl * 32 + nh * 16 + cl;
    di = (size_t)sl * 65536 + (((size_t)(nh * 4 + gt) * 16 + kt) * 64 + ln) * 8 + j;
  } else {
    int jt = (r >> 13) & 1, nh = (r >> 14) & 1, sl = (r >> 15) & 31;
    W = (mat == 1) ? Wx1 : Wh1;
    int gate = jt * 2 + (cl >> 3);
    gcol = gate * 512 + sl * 16 + nh * 8 + (cl & 7);
    di = (size_t)mat * 1048576 + (size_t)sl * 32768 +
         (((size_t)(nh * 2 + jt) * 16 + kt) * 64 + ln) * 8 + j;
  }
  dst[di] = (f16)W[(size_t)k * 2048 + gcol];
}

// ---------------------------------------------------------------------------
__global__ void reduce_out(const float* __restrict__ part8,
                           const float* __restrict__ bfp,
                           float* __restrict__ out) {
  int g = blockIdx.x * 256 + threadIdx.x;   // 262144 = b*1024+t
  float v = bfp[0];
#pragma unroll
  for (int j = 0; j < 8; ++j) v += part8[(size_t)j * (NB * NT_) + g];
  out[g] = v;
}

// ---------------------------------------------------------------------------
// h transport layouts (slice-major, per-WG-contiguous; R7-verified):
//   p[slot][c<4][sl<16][row<64][unit<32]  (elem = slot*131072 + c*32768
//                                          + sl*2048 + row*32 + unit)
//   q[slot][c<4][sl<32][row<64][unit<16]  (elem = slot*131072 + c*32768
//                                          + sl*1024 + row*16 + unit)
__global__ __launch_bounds__(128, 1) void lstm_main(
    const float* __restrict__ xT,       // [T][B]
    const f16*  __restrict__ wsl,       // tiled fp16 weights (6 MB)
    const float* __restrict__ wx0,      // [2048]
    const float* __restrict__ bias0,    // [2048]
    const float* __restrict__ bias1,    // [2048]
    const float* __restrict__ wf,       // [512]
    unsigned short* p_hi, unsigned short* p_lo,   // [RING][...] slice-major
    unsigned short* q_hi, unsigned short* q_lo,   // [RING][...] slice-major
    unsigned int* pf,                   // [4][32] L0 slice flags (16 used/chunk)
    unsigned int* qf,                   // [4][32] L1 slice flags
    float* part8)                       // [8][B][T]
{
  extern __shared__ char smem[];
  const int tid = threadIdx.x;
  const int wv = tid >> 6, ln = tid & 63;     // 2 waves per WG
  const int qd = ln >> 4, cl = ln & 15;
  const int bx = blockIdx.x;
  const int r8 = bx & 7, idx = bx >> 3;
  const bool isL0 = !(r8 & 1);
  const int c = r8 >> 1;
  const int sl = idx;
  if (isL0 && idx >= 16) return;        // 64 spare WGs exit (uniform per WG)
  const float LO = 1.0f / 1024.0f;

  // ---- stage weight slice(s) into LDS (once) ----
  if (isL0) {
    const int4* s0 = (const int4*)wsl + (size_t)sl * 8192;           // 128 KB
    int4* d = (int4*)smem;
    for (int i = tid; i < 8192; i += 128) d[i] = s0[i];
  } else {
    const int4* s1 = (const int4*)wsl + 131072 + (size_t)sl * 4096;  // Wx1 64 KB
    const int4* s2 = (const int4*)wsl + 262144 + (size_t)sl * 4096;  // Wh1 64 KB
    int4* d = (int4*)smem;
    for (int i = tid; i < 4096; i += 128) { d[i] = s1[i]; d[4096 + i] = s2[i]; }
  }
  __syncthreads();

  unsigned* pfc = pf + c * 32;
  unsigned* qfc = qf + c * 32;

  if (isL0) {
    // ======== layer 0 ========
    // wave wv = 32-row half; computes ALL 8 gate groups (both nh) x 2 rt.
    // Per wave/step: 64 A-loads (no dup), 128 B-LDS reads, 512 MFMA.
    const int rb0 = c * 64 + wv * 32;                    // global batch row
    float wx0v[2][4], b0c[2][4];
#pragma unroll
    for (int nh = 0; nh < 2; ++nh)
#pragma unroll
      for (int g = 0; g < 4; ++g) {
        int gc = g * 512 + sl * 32 + nh * 16 + cl;
        wx0v[nh][g] = wx0[gc];
        b0c[nh][g] = bias0[gc];
      }
    float cst[2][2][4] = {};                             // [nh][rt][e]
    // combined step-start poll: lanes 0-15 & 48-63 -> pf>=s (peers done s-1),
    // lanes 16-47 -> qf>=s-RING+1 (ring-overwrite guard), one round trip.
    const bool isq = (ln >= 16 && ln < 48);
    const unsigned* pwa = isq ? (qfc + (ln & 31)) : (pfc + (ln & 15));
    const f16x8* wl = (const f16x8*)smem;
    f16* sh  = (f16*)(smem + 131072);    // [64][32] hi stage (4 KB)
    f16* slo = sh + 2048;                // [64][32] lo stage (4 KB)

    for (int s = 0; s < NT_; ++s) {
      // ---- ring-epoch L1/L2 invalidate (addresses reused every 16 steps) ----
      if ((s & (RING - 1)) == 0 && s) {
        __syncthreads();
        if (wv == 0)
          asm volatile("buffer_inv sc1\n\ts_waitcnt vmcnt(0)" ::: "memory");
        __syncthreads();
      }
      const int slot_r = (s + RING - 1) & (RING - 1);   // h_{s-1}
      const int slot_w = s & (RING - 1);                // h_s
      // x prefetch — independent of flags, issue before the poll
      float4 xv[2];
#pragma unroll
      for (int rt = 0; rt < 2; ++rt)
        xv[rt] = *(const float4*)(xT + s * NB + rb0 + rt * 16 + qd * 4);
      if (s) {
        unsigned thr = isq ? (s >= RING ? (unsigned)(s - RING + 1) : 0u)
                           : (unsigned)s;
        pollr(pwa, thr);
      }
      // ---- preload ALL A fragments (h_{s-1} hi/lo) into registers ----
      f16x8 Ah[16][2], Al[16][2];
      {
        const f16* bh = (const f16*)p_hi + (size_t)slot_r * SLOT + (size_t)c * 32768 + qd * 8;
        const f16* bl = (const f16*)p_lo + (size_t)slot_r * SLOT + (size_t)c * 32768 + qd * 8;
#pragma unroll
        for (int kt = 0; kt < 16; ++kt)
#pragma unroll
          for (int rt = 0; rt < 2; ++rt) {
            int lr = wv * 32 + rt * 16 + cl;             // chunk-local row
            size_t off = (size_t)kt * 2048 + lr * 32;
            Ah[kt][rt] = *(const f16x8*)(bh + off);
            Al[kt][rt] = *(const f16x8*)(bl + off);
          }
      }
      f32x4 acc[8][2], accL[8][2];
#pragma unroll
      for (int t8 = 0; t8 < 8; ++t8)
#pragma unroll
        for (int rt = 0; rt < 2; ++rt) {
          acc[t8][rt] = (f32x4){0.f,0.f,0.f,0.f};
          accL[t8][rt] = (f32x4){0.f,0.f,0.f,0.f};
        }
#pragma unroll
      for (int kt = 0; kt < 16; ++kt) {
#pragma unroll
        for (int t8 = 0; t8 < 8; ++t8) {                 // t8 = nh*4 + gate
          f16x8 bw = wl[(t8 * 16 + kt) * 64 + ln];
#pragma unroll
          for (int rt = 0; rt < 2; ++rt) {
            acc[t8][rt]  = __builtin_amdgcn_mfma_f32_16x16x32_f16(Ah[kt][rt], bw, acc[t8][rt], 0, 0, 0);
            accL[t8][rt] = __builtin_amdgcn_mfma_f32_16x16x32_f16(Al[kt][rt], bw, accL[t8][rt], 0, 0, 0);
          }
        }
      }
      // ---- epilogue -> LDS stage ----
#pragma unroll
      for (int rt = 0; rt < 2; ++rt)
#pragma unroll
        for (int e = 0; e < 4; ++e) {
          float xe = (e == 0) ? xv[rt].x : (e == 1) ? xv[rt].y : (e == 2) ? xv[rt].z : xv[rt].w;
          int r = wv * 32 + rt * 16 + qd * 4 + e;
#pragma unroll
          for (int nh = 0; nh < 2; ++nh) {
            float gi = acc[nh*4+0][rt][e] + accL[nh*4+0][rt][e] * LO + xe * wx0v[nh][0] + b0c[nh][0];
            float gf = acc[nh*4+1][rt][e] + accL[nh*4+1][rt][e] * LO + xe * wx0v[nh][1] + b0c[nh][1];
            float gg = acc[nh*4+2][rt][e] + accL[nh*4+2][rt][e] * LO + xe * wx0v[nh][2] + b0c[nh][2];
            float go = acc[nh*4+3][rt][e] + accL[nh*4+3][rt][e] * LO + xe * wx0v[nh][3] + b0c[nh][3];
            float ii = sigm(gi), ff = sigm(gf), tg = tanhx(gg), oo = sigm(go);
            cst[nh][rt][e] = ff * cst[nh][rt][e] + ii * tg;
            float h = oo * tanhx(cst[nh][rt][e]);
            f16 hh = (f16)h;
            int su = r * 32 + nh * 16 + cl;
            sh[su]  = hh;
            slo[su] = (f16)((h - (float)hh) * 1024.0f);
          }
        }
      __syncthreads();
      // ---- coop store: 2 x 4KB contiguous, 8B/lane, full-line coverage ----
      {
        unsigned short* bh = p_hi + (size_t)slot_w * SLOT + (size_t)c * 32768 + (size_t)sl * 2048;
        unsigned short* bl = p_lo + (size_t)slot_w * SLOT + (size_t)c * 32768 + (size_t)sl * 2048;
#pragma unroll
        for (int i = tid; i < 1024; i += 128) {
          int strm = i >> 9, pc = i & 511;               // 8B piece index
          const f16* src = (strm ? slo : sh) + pc * 4;
          st8((strm ? bl : bh) + pc * 4, *(const u64*)src);
        }
      }
      __syncthreads();   // all waves' stores vmcnt-drained at LLC before barrier
      if (tid == 0)
        __hip_atomic_store(pfc + sl, (unsigned)(s + 1),
                           __ATOMIC_RELAXED, __HIP_MEMORY_SCOPE_AGENT);
    }
  } else {
    // ======== layer 1: q_s = LSTM(p_s, q_{s-1}) ========
    // wave wv = 32-row half; all 4 t4 groups x 2 rt. B-LDS reads shared
    // across rt -> 128 reads/wave/step (halved per CU vs R7).
    int u = cl & 7, g01 = cl >> 3;
    const bool hiH = (cl < 8);
    float b1c0[2], b1c1[2], wfv[2];
#pragma unroll
    for (int nh = 0; nh < 2; ++nh) {
      int base = sl * 16 + nh * 8 + u;
      b1c0[nh] = bias1[g01 * 512 + base];
      b1c1[nh] = bias1[(2 + g01) * 512 + base];
      wfv[nh] = wf[base];
    }
    float cst[2][2][4] = {};                             // [nh][rt][e]
    unsigned pf_seen = 0;               // per-lane cached flag (ln&15), monotonic
    const f16x8* wx_ = (const f16x8*)smem;
    const f16x8* wh_ = (const f16x8*)(smem + 65536);
    f16* sh  = (f16*)(smem + 131072);   // [64][16] hi stage (2 KB)
    f16* slo = sh + 1024;               // [64][16] lo stage (2 KB)

    for (int s = 0; s < NT_; ++s) {
      if ((s & (RING - 1)) == 0 && s) {
        __syncthreads();
        if (wv == 0)
          asm volatile("buffer_inv sc1\n\ts_waitcnt vmcnt(0)" ::: "memory");
        __syncthreads();
      }
      const int slot_r = (s + RING - 1) & (RING - 1);
      const int slot_w = s & (RING - 1);
      if (s) pollr(qfc + (ln & 31), (unsigned)s);       // peers done s-1
      // preload q_{s-1} fragments (slice-major, 16-unit slices: unit
      // kt*32+qd*8 -> slice kt*2+(qd>>1), offset (qd&1)*8)
      f16x8 AqH[16][2], AqL[16][2];
      {
        const f16* bq = (const f16*)q_hi + (size_t)slot_r * SLOT + (size_t)c * 32768 +
                        (qd >> 1) * 1024 + (qd & 1) * 8;
        const f16* bql = (const f16*)q_lo + (size_t)slot_r * SLOT + (size_t)c * 32768 +
                         (qd >> 1) * 1024 + (qd & 1) * 8;
#pragma unroll
        for (int kt = 0; kt < 16; ++kt)
#pragma unroll
          for (int rt = 0; rt < 2; ++rt) {
            int lr = wv * 32 + rt * 16 + cl;
            size_t off = (size_t)kt * 2048 + lr * 16;
            AqH[kt][rt] = *(const f16x8*)(bq + off);
            AqL[kt][rt] = *(const f16x8*)(bql + off);
          }
      }
      // runahead: if cached pf already shows L0 done step s, issue p loads NOW
      const f16* bp  = (const f16*)p_hi + (size_t)slot_w * SLOT + (size_t)c * 32768 + qd * 8;
      const f16* bpl = (const f16*)p_lo + (size_t)slot_w * SLOT + (size_t)c * 32768 + qd * 8;
      bool early = __all((int)(pf_seen >= (unsigned)(s + 1)));
      f16x8 ApH[16][2], ApL[16][2];
      if (early) {
#pragma unroll
        for (int kt = 0; kt < 16; ++kt)
#pragma unroll
          for (int rt = 0; rt < 2; ++rt) {
            int lr = wv * 32 + rt * 16 + cl;
            size_t off = (size_t)kt * 2048 + lr * 32;
            ApH[kt][rt] = *(const f16x8*)(bp + off);
            ApL[kt][rt] = *(const f16x8*)(bpl + off);
          }
      }
      f32x4 acc[4][2], accL[4][2];
#pragma unroll
      for (int t4 = 0; t4 < 4; ++t4)
#pragma unroll
        for (int rt = 0; rt < 2; ++rt) {
          acc[t4][rt] = (f32x4){0.f,0.f,0.f,0.f};
          accL[t4][rt] = (f32x4){0.f,0.f,0.f,0.f};
        }
      // phase 1: q_{s-1} @ Wh1
#pragma unroll
      for (int kt = 0; kt < 16; ++kt) {
#pragma unroll
        for (int t4 = 0; t4 < 4; ++t4) {                 // t4 = nh*2 + jt
          f16x8 bw = wh_[(t4 * 16 + kt) * 64 + ln];
#pragma unroll
          for (int rt = 0; rt < 2; ++rt) {
            acc[t4][rt]  = __builtin_amdgcn_mfma_f32_16x16x32_f16(AqH[kt][rt], bw, acc[t4][rt], 0, 0, 0);
            accL[t4][rt] = __builtin_amdgcn_mfma_f32_16x16x32_f16(AqL[kt][rt], bw, accL[t4][rt], 0, 0, 0);
          }
        }
      }
      if (!early) {
        pf_seen = pollr(pfc + (ln & 15), (unsigned)(s + 1));
#pragma unroll
        for (int kt = 0; kt < 16; ++kt)
#pragma unroll
          for (int rt = 0; rt < 2; ++rt) {
            int lr = wv * 32 + rt * 16 + cl;
            size_t off = (size_t)kt * 2048 + lr * 32;
            ApH[kt][rt] = *(const f16x8*)(bp + off);
            ApL[kt][rt] = *(const f16x8*)(bpl + off);
          }
      }
      // phase 2: p_s @ Wx1
#pragma unroll
      for (int kt = 0; kt < 16; ++kt) {
#pragma unroll
        for (int t4 = 0; t4 < 4; ++t4) {
          f16x8 bw = wx_[(t4 * 16 + kt) * 64 + ln];
#pragma unroll
          for (int rt = 0; rt < 2; ++rt) {
            acc[t4][rt]  = __builtin_amdgcn_mfma_f32_16x16x32_f16(ApH[kt][rt], bw, acc[t4][rt], 0, 0, 0);
            accL[t4][rt] = __builtin_amdgcn_mfma_f32_16x16x32_f16(ApL[kt][rt], bw, accL[t4][rt], 0, 0, 0);
          }
        }
      }
      // ---- epilogue -> LDS stage ----
      float po[2][4];
#pragma unroll
      for (int rt = 0; rt < 2; ++rt)
#pragma unroll
        for (int e = 0; e < 4; ++e) {
          po[rt][e] = 0.0f;
          int r = wv * 32 + rt * 16 + qd * 4 + e;
#pragma unroll
          for (int nh = 0; nh < 2; ++nh) {
            float v0 = acc[nh*2+0][rt][e] + accL[nh*2+0][rt][e] * LO + b1c0[nh];   // i / f
            float v1 = acc[nh*2+1][rt][e] + accL[nh*2+1][rt][e] * LO + b1c1[nh];   // g / o
            float w0 = __shfl_xor(v0, 8, 16);
            float w1 = __shfl_xor(v1, 8, 16);
            float gi = hiH ? v0 : w0;
            float gf = hiH ? w0 : v0;
            float gg = hiH ? v1 : w1;
            float go = hiH ? w1 : v1;
            float ii = sigm(gi), ff = sigm(gf), tg = tanhx(gg), oo = sigm(go);
            cst[nh][rt][e] = ff * cst[nh][rt][e] + ii * tg;
            float h = oo * tanhx(cst[nh][rt][e]);
            int su = r * 16 + nh * 8 + u;
            if (hiH) {
              sh[su] = (f16)h;
            } else {
              f16 hh = (f16)h;
              slo[su] = (f16)((h - (float)hh) * 1024.0f);
            }
            po[rt][e] += hiH ? wfv[nh] * h : 0.0f;
          }
        }
      __syncthreads();
      // ---- coop store: 2 x 2KB contiguous, 8B/lane, full-line coverage ----
      {
        unsigned short* bhq = q_hi + (size_t)slot_w * SLOT + (size_t)c * 32768 + (size_t)sl * 1024;
        unsigned short* blq = q_lo + (size_t)slot_w * SLOT + (size_t)c * 32768 + (size_t)sl * 1024;
#pragma unroll
        for (int i = tid; i < 512; i += 128) {
          int strm = i >> 8, pc = i & 255;               // 8B piece index
          const f16* src = (strm ? slo : sh) + pc * 4;
          st8((strm ? blq : bhq) + pc * 4, *(const u64*)src);
        }
      }
      __syncthreads();   // stores drained at LLC
      if (tid == 0)
        __hip_atomic_store(qfc + sl, (unsigned)(s + 1),
                           __ATOMIC_RELAXED, __HIP_MEMORY_SCOPE_AGENT);
      // deferred head-output reduce + atomic (off the q->q critical path)
#pragma unroll
      for (int rt = 0; rt < 2; ++rt)
#pragma unroll
        for (int e = 0; e < 4; ++e) {
          float r = po[rt][e];
#pragma unroll
          for (int m = 1; m < 16; m <<= 1) r += __shfl_xor(r, m, 16);
          if (cl == 0)
            atomicAdd(part8 + (size_t)(sl & 7) * (NB * NT_) +
                          (size_t)(c * 64 + wv * 32 + rt * 16 + qd * 4 + e) * NT_ + s, r);
        }
    }
  }
}

// ---------------------------------------------------------------------------
extern "C" void kernel_launch(void* const* d_in, const int* in_sizes, int n_in,
                              void* d_out, int out_size, void* d_ws, size_t ws_size,
                              hipStream_t stream) {
  (void)in_sizes; (void)n_in; (void)out_size; (void)ws_size;
  const float* inp = (const float*)d_in[0];
  const float* Wx0 = (const float*)d_in[1];
  const float* Wh0 = (const float*)d_in[2];
  const float* b0  = (const float*)d_in[3];
  const float* Wx1 = (const float*)d_in[4];
  const float* Wh1 = (const float*)d_in[5];
  const float* b1  = (const float*)d_in[6];
  const float* Wf  = (const float*)d_in[7];
  const float* bf  = (const float*)d_in[8];

  const size_t MB = 1u << 20;
  const size_t OFF_W    = 0;                 // 6 MiB tiled fp16 weights
  const size_t OFF_XT   = 6 * MB;            // 1 MiB
  const size_t OFF_PHI  = 7 * MB;            // 4 MiB (RING x 256 KB)
  const size_t OFF_PLO  = 11 * MB;
  const size_t OFF_QHI  = 15 * MB;
  const size_t OFF_QLO  = 19 * MB;
  const size_t OFF_PART = 23 * MB;           // 8 MiB
  const size_t OFF_CTR  = 31 * MB;           // flags: pf 512 B + qf 512 B

  char* ws = (char*)d_ws;
  f16* wsl = (f16*)(ws + OFF_W);
  float* xT = (float*)(ws + OFF_XT);
  unsigned short* phi = (unsigned short*)(ws + OFF_PHI);
  unsigned short* plo = (unsigned short*)(ws + OFF_PLO);
  unsigned short* qhi = (unsigned short*)(ws + OFF_QHI);
  unsigned short* qlo = (unsigned short*)(ws + OFF_QLO);
  float* part8 = (float*)(ws + OFF_PART);
  unsigned int* pfl = (unsigned int*)(ws + OFF_CTR);
  unsigned int* qfl = pfl + 128;
  float* out = (float*)d_out;

  (void)hipFuncSetAttribute((const void*)lstm_main,
                            hipFuncAttributeMaxDynamicSharedMemorySize, 139264);

  // zero rings + partials + flags (contiguous)
  (void)hipMemsetAsync(ws + OFF_PHI, 0, (OFF_CTR + 1024) - OFF_PHI, stream);

  prep_xT<<<1024, 256, 0, stream>>>(inp, xT);
  prep_w<<<12288, 256, 0, stream>>>(Wh0, Wx1, Wh1, wsl);

  lstm_main<<<256, 128, 139264, stream>>>(xT, wsl, Wx0, b0, b1, Wf,
                                          phi, plo, qhi, qlo, pfl, qfl, part8);

  reduce_out<<<1024, 256, 0, stream>>>(part8, bf, out);
}

// Round 5
// 10147.255 us; speedup vs baseline: 2.6222x; 2.6222x over previous
//
#include <hip/hip_runtime.h>

// ============================================================================
// 2-layer LSTM (B=256, T=1024, H=512, in=1) + linear head. fp32 in/out.
//
// R9 = R7 (verified 10.29ms) + poll-contention cuts. R8 (2-wave rebalance)
// regressed 2.6x via VGPR spill (VGPR=256 capped, WRITE 8.5GB scratch) ->
// reverted. Chain model: wall-period == L0->L0 chain latency (~10us);
// store-drain fix (R7) removed ~2.7us; remaining fat hypothesized in flag
// polling: ~192 waves/chunk spin agent-scope loads on 2 LLC lines ->
// LLC-bank queueing inflates detect + neighbors.
//  1. Leader-wave poll: wave 0 polls, peers wait at syncthreads (4x less).
//  2. Flag replication x4: producer stores 4 replica lines (512B apart);
//     consumer reads replica sl&3 (per-line rate /4).
//  3. s_sleep(2)->s_sleep(1).
// Frozen: slice-major transport + full-line coop st8 stores (R7 win),
// reg-preloaded A, L1 runahead (per-wave cached pf), epoch buffer_inv sc1,
// deferred head atomic, 256 thr / 4 waves, math bit-identical.
// Predicted: contention-bound -> 6-7.5ms, MfmaUtil ~20; flat -> raw-RT
// bound, R10 = per-producer pipelined flags + speculative fused loads.
// ============================================================================

typedef _Float16 f16;
typedef _Float16 f16x8 __attribute__((ext_vector_type(8)));
typedef float f32x4 __attribute__((ext_vector_type(4)));
typedef unsigned long long u64;

#define NB 256
#define NT_ 1024
#define NH 512
#define RING 16
#define SLOT (NB * NH)

__device__ __forceinline__ float sigm(float x)  { return 1.0f / (1.0f + __expf(-x)); }
__device__ __forceinline__ float tanhx(float x) { return 2.0f / (1.0f + __expf(-2.0f * x)) - 1.0f; }

// 8B agent-visible write-through store (verified R3/R4/R7 transport primitive)
__device__ __forceinline__ void st8(unsigned short* p, u64 v) {
  __hip_atomic_store((u64*)p, v, __ATOMIC_RELAXED, __HIP_MEMORY_SCOPE_AGENT);
}
__device__ __forceinline__ void stf(unsigned* p, unsigned v) {
  __hip_atomic_store(p, v, __ATOMIC_RELAXED, __HIP_MEMORY_SCOPE_AGENT);
}
__device__ __forceinline__ unsigned ldf(const unsigned* p) {
  return __hip_atomic_load(p, __ATOMIC_RELAXED, __HIP_MEMORY_SCOPE_AGENT);
}
// Poll until every lane's flag (per-lane address/threshold) passes. Returns
// the last value this lane read (for runahead caching — flags are monotonic).
__device__ __forceinline__ unsigned pollr(const unsigned* a, unsigned thr) {
  unsigned v;
  for (;;) {
    v = ldf(a);
    if (!~__ballot(v >= thr)) break;
    __builtin_amdgcn_s_sleep(1);
  }
  asm volatile("" ::: "memory");
  return v;
}

// ---------------------------------------------------------------------------
__global__ void prep_xT(const float* __restrict__ inp, float* __restrict__ xT) {
  int g = blockIdx.x * 256 + threadIdx.x;
  int t = g >> 8, b = g & 255;
  xT[t * NB + b] = inp[b * NT_ + t];
}

// ---------------------------------------------------------------------------
// fp32 -> fp16 weights in MFMA B-fragment order (verified R3; unchanged).
// L0 (Wh0): 16 slices x [nh<2][gate<4][kt<16][lane<64][j<8]; slice=65536 elems.
// L1 (Wx1, Wh1): 32 slices x [nh<2][jt<2][kt<16][lane<64][j<8]; slice=32768.
__global__ void prep_w(const float* __restrict__ Wh0,
                       const float* __restrict__ Wx1,
                       const float* __restrict__ Wh1,
                       f16* __restrict__ dst) {
  int g = blockIdx.x * 256 + threadIdx.x;   // 3 * 2^20 threads
  int mat = g >> 20;
  int r = g & 0xFFFFF;
  int j = r & 7, ln = (r >> 3) & 63, kt = (r >> 9) & 15;
  int cl = ln & 15, qd = ln >> 4;
  int k = kt * 32 + qd * 8 + j;
  size_t di; int gcol; const float* W;
  if (mat == 0) {
    int gt = (r >> 13) & 3, nh = (r >> 15) & 1, sl = (r >> 16) & 15;
    W = Wh0;
    gcol = gt * 512 + sl * 32 + nh * 16 + cl;
    di = (size_t)sl * 65536 + (((size_t)(nh * 4 + gt) * 16 + kt) * 64 + ln) * 8 + j;
  } else {
    int jt = (r >> 13) & 1, nh = (r >> 14) & 1, sl = (r >> 15) & 31;
    W = (mat == 1) ? Wx1 : Wh1;
    int gate = jt * 2 + (cl >> 3);
    gcol = gate * 512 + sl * 16 + nh * 8 + (cl & 7);
    di = (size_t)mat * 1048576 + (size_t)sl * 32768 +
         (((size_t)(nh * 2 + jt) * 16 + kt) * 64 + ln) * 8 + j;
  }
  dst[di] = (f16)W[(size_t)k * 2048 + gcol];
}

// ---------------------------------------------------------------------------
__global__ void reduce_out(const float* __restrict__ part8,
                           const float* __restrict__ bfp,
                           float* __restrict__ out) {
  int g = blockIdx.x * 256 + threadIdx.x;   // 262144 = b*1024+t
  float v = bfp[0];
#pragma unroll
  for (int j = 0; j < 8; ++j) v += part8[(size_t)j * (NB * NT_) + g];
  out[g] = v;
}

// ---------------------------------------------------------------------------
// h transport layouts (slice-major, per-WG-contiguous; R7-verified):
//   p[slot][c<4][sl<16][row<64][unit<32]  q[slot][c<4][sl<32][row<64][unit<16]
// Flags: [rep<4][c<4][32] per type; replicas 512B apart. Producer stores all
// 4 replicas; consumer reads replica (sl&3).
__global__ __launch_bounds__(256, 1) void lstm_main(
    const float* __restrict__ xT,       // [T][B]
    const f16*  __restrict__ wsl,       // tiled fp16 weights (6 MB)
    const float* __restrict__ wx0,      // [2048]
    const float* __restrict__ bias0,    // [2048]
    const float* __restrict__ bias1,    // [2048]
    const float* __restrict__ wf,       // [512]
    unsigned short* p_hi, unsigned short* p_lo,   // [RING][...] slice-major
    unsigned short* q_hi, unsigned short* q_lo,   // [RING][...] slice-major
    unsigned int* pf,                   // [4 rep][4 c][32] L0 slice flags
    unsigned int* qf,                   // [4 rep][4 c][32] L1 slice flags
    float* part8)                       // [8][B][T]
{
  extern __shared__ char smem[];
  const int tid = threadIdx.x;
  const int wv = tid >> 6, ln = tid & 63;
  const int qd = ln >> 4, cl = ln & 15;
  const int bx = blockIdx.x;
  const int r8 = bx & 7, idx = bx >> 3;
  const bool isL0 = !(r8 & 1);
  const int c = r8 >> 1;
  const int sl = idx;
  if (isL0 && idx >= 16) return;        // 64 spare WGs exit (uniform per WG)
  const float LO = 1.0f / 1024.0f;

  // ---- stage weight slice(s) into LDS (once) ----
  if (isL0) {
    const int4* s0 = (const int4*)wsl + (size_t)sl * 8192;           // 128 KB
    int4* d = (int4*)smem;
    for (int i = tid; i < 8192; i += 256) d[i] = s0[i];
  } else {
    const int4* s1 = (const int4*)wsl + 131072 + (size_t)sl * 4096;  // Wx1 64 KB
    const int4* s2 = (const int4*)wsl + 262144 + (size_t)sl * 4096;  // Wh1 64 KB
    int4* d = (int4*)smem;
    for (int i = tid; i < 4096; i += 256) { d[i] = s1[i]; d[4096 + i] = s2[i]; }
  }
  __syncthreads();

  // consumer replica bases (spread over 4 lines); producer writes all 4
  unsigned* pfc = pf + (sl & 3) * 128 + c * 32;
  unsigned* qfc = qf + (sl & 3) * 128 + c * 32;

  if (isL0) {
    // ======== layer 0 ========
    // wave = (nh = wv>>1, rhalf = wv&1). 256 MFMA/wave/step, A in regs.
    const int nh = wv >> 1, rhalf = wv & 1;
    const int rb0 = c * 64 + rhalf * 32;                 // global batch row
    float wx0v[4], b0c[4];
#pragma unroll
    for (int g = 0; g < 4; ++g) {
      int gc = g * 512 + sl * 32 + nh * 16 + cl;
      wx0v[g] = wx0[gc];
      b0c[g] = bias0[gc];
    }
    float cst[2][4] = {{0.f,0.f,0.f,0.f},{0.f,0.f,0.f,0.f}};
    // combined step-start poll (wave 0 only): lanes 0-15 & 48-63 -> pf>=s,
    // lanes 16-47 -> qf>=s-RING+1 (ring-overwrite guard), one round trip.
    const bool isq = (ln >= 16 && ln < 48);
    const unsigned* pwa = isq ? (qfc + (ln & 31)) : (pfc + (ln & 15));
    const f16x8* wl = (const f16x8*)smem;
    f16* sh  = (f16*)(smem + 131072);    // [64][32] hi stage (4 KB)
    f16* slo = sh + 2048;                // [64][32] lo stage (4 KB)

    for (int s = 0; s < NT_; ++s) {
      // ---- ring-epoch L1/L2 invalidate (addresses reused every 16 steps) ----
      if ((s & (RING - 1)) == 0 && s) {
        __syncthreads();
        if (wv == 0)
          asm volatile("buffer_inv sc1\n\ts_waitcnt vmcnt(0)" ::: "memory");
        __syncthreads();
      }
      const int slot_r = (s + RING - 1) & (RING - 1);   // h_{s-1}
      const int slot_w = s & (RING - 1);                // h_s
      // x prefetch — independent of flags, issue before the poll
      float4 xv[2];
#pragma unroll
      for (int rt = 0; rt < 2; ++rt)
        xv[rt] = *(const float4*)(xT + s * NB + rb0 + rt * 16 + qd * 4);
      if (s) {
        unsigned thr = isq ? (s >= RING ? (unsigned)(s - RING + 1) : 0u)
                           : (unsigned)s;
        if (wv == 0) pollr(pwa, thr);    // leader poll (4x less flag traffic)
        __syncthreads();
      }
      // ---- preload ALL A fragments (h_{s-1} hi/lo) into registers ----
      // slice-major: slice kt holds units kt*32..+32
      f16x8 Ah[16][2], Al[16][2];
      {
        const f16* bh = (const f16*)p_hi + (size_t)slot_r * SLOT + (size_t)c * 32768 + qd * 8;
        const f16* bl = (const f16*)p_lo + (size_t)slot_r * SLOT + (size_t)c * 32768 + qd * 8;
#pragma unroll
        for (int kt = 0; kt < 16; ++kt)
#pragma unroll
          for (int rt = 0; rt < 2; ++rt) {
            int lr = rhalf * 32 + rt * 16 + cl;          // chunk-local row
            size_t off = (size_t)kt * 2048 + lr * 32;
            Ah[kt][rt] = *(const f16x8*)(bh + off);
            Al[kt][rt] = *(const f16x8*)(bl + off);
          }
      }
      f32x4 acc[4][2], accL[4][2];
#pragma unroll
      for (int g = 0; g < 4; ++g)
#pragma unroll
        for (int rt = 0; rt < 2; ++rt) {
          acc[g][rt] = (f32x4){0.f,0.f,0.f,0.f};
          accL[g][rt] = (f32x4){0.f,0.f,0.f,0.f};
        }
#pragma unroll
      for (int kt = 0; kt < 16; ++kt) {
#pragma unroll
        for (int g = 0; g < 4; ++g) {
          f16x8 bw = wl[((nh * 4 + g) * 16 + kt) * 64 + ln];
#pragma unroll
          for (int rt = 0; rt < 2; ++rt) {
            acc[g][rt]  = __builtin_amdgcn_mfma_f32_16x16x32_f16(Ah[kt][rt], bw, acc[g][rt], 0, 0, 0);
            accL[g][rt] = __builtin_amdgcn_mfma_f32_16x16x32_f16(Al[kt][rt], bw, accL[g][rt], 0, 0, 0);
          }
        }
      }
      // ---- epilogue -> LDS stage ----
#pragma unroll
      for (int rt = 0; rt < 2; ++rt)
#pragma unroll
        for (int e = 0; e < 4; ++e) {
          float xe = (e == 0) ? xv[rt].x : (e == 1) ? xv[rt].y : (e == 2) ? xv[rt].z : xv[rt].w;
          float gi = acc[0][rt][e] + accL[0][rt][e] * LO + xe * wx0v[0] + b0c[0];
          float gf = acc[1][rt][e] + accL[1][rt][e] * LO + xe * wx0v[1] + b0c[1];
          float gg = acc[2][rt][e] + accL[2][rt][e] * LO + xe * wx0v[2] + b0c[2];
          float go = acc[3][rt][e] + accL[3][rt][e] * LO + xe * wx0v[3] + b0c[3];
          float ii = sigm(gi), ff = sigm(gf), tg = tanhx(gg), oo = sigm(go);
          cst[rt][e] = ff * cst[rt][e] + ii * tg;
          float h = oo * tanhx(cst[rt][e]);
          f16 hh = (f16)h;
          int su = (rhalf * 32 + rt * 16 + qd * 4 + e) * 32 + nh * 16 + cl;
          sh[su]  = hh;
          slo[su] = (f16)((h - (float)hh) * 1024.0f);
        }
      __syncthreads();
      // ---- coop store: 2 x 4KB contiguous, 8B/lane, full-line coverage ----
      {
        unsigned short* bh = p_hi + (size_t)slot_w * SLOT + (size_t)c * 32768 + (size_t)sl * 2048;
        unsigned short* bl = p_lo + (size_t)slot_w * SLOT + (size_t)c * 32768 + (size_t)sl * 2048;
#pragma unroll
        for (int i = tid; i < 1024; i += 256) {
          int strm = i >> 9, pc = i & 511;               // 8B piece index
          const f16* src = (strm ? slo : sh) + pc * 4;
          st8((strm ? bl : bh) + pc * 4, *(const u64*)src);
        }
      }
      __syncthreads();   // all waves' stores vmcnt-drained at LLC before barrier
      if (tid < 4)       // store all 4 replicas (512B apart)
        stf(pf + tid * 128 + c * 32 + sl, (unsigned)(s + 1));
    }
  } else {
    // ======== layer 1: q_s = LSTM(p_s, q_{s-1}) ========
    int u = cl & 7, g01 = cl >> 3;
    const bool hiH = (cl < 8);
    float b1c0[2], b1c1[2], wfv[2];
#pragma unroll
    for (int nh = 0; nh < 2; ++nh) {
      int base = sl * 16 + nh * 8 + u;
      b1c0[nh] = bias1[g01 * 512 + base];
      b1c1[nh] = bias1[(2 + g01) * 512 + base];
      wfv[nh] = wf[base];
    }
    const int lr = wv * 16 + cl;                        // chunk-local row
    float cst[2][4] = {{0.f,0.f,0.f,0.f},{0.f,0.f,0.f,0.f}};
    unsigned pf_seen = 0;               // per-lane cached flag (ln&15), monotonic
    const f16x8* wx_ = (const f16x8*)smem;
    const f16x8* wh_ = (const f16x8*)(smem + 65536);
    f16* sh  = (f16*)(smem + 131072);   // [64][16] hi stage (2 KB)
    f16* slo = sh + 1024;               // [64][16] lo stage (2 KB)

    for (int s = 0; s < NT_; ++s) {
      if ((s & (RING - 1)) == 0 && s) {
        __syncthreads();
        if (wv == 0)
          asm volatile("buffer_inv sc1\n\ts_waitcnt vmcnt(0)" ::: "memory");
        __syncthreads();
      }
      const int slot_r = (s + RING - 1) & (RING - 1);
      const int slot_w = s & (RING - 1);
      if (s) {                                           // peers done s-1
        if (wv == 0) pollr(qfc + (ln & 31), (unsigned)s);
        __syncthreads();
      }
      // preload q_{s-1} fragments (slice-major, 16-unit slices: unit
      // kt*32+qd*8 -> slice kt*2+(qd>>1), offset (qd&1)*8)
      const f16* aqh = (const f16*)q_hi + (size_t)slot_r * SLOT + (size_t)c * 32768 +
                       (qd >> 1) * 1024 + lr * 16 + (qd & 1) * 8;
      const f16* aql = (const f16*)q_lo + (size_t)slot_r * SLOT + (size_t)c * 32768 +
                       (qd >> 1) * 1024 + lr * 16 + (qd & 1) * 8;
      f16x8 Aq[16][2];
#pragma unroll
      for (int kt = 0; kt < 16; ++kt) {
        Aq[kt][0] = *(const f16x8*)(aqh + kt * 2048);
        Aq[kt][1] = *(const f16x8*)(aql + kt * 2048);
      }
      // runahead: if cached pf already shows L0 done step s, issue p loads NOW
      const f16* aph = (const f16*)p_hi + (size_t)slot_w * SLOT + (size_t)c * 32768 +
                       lr * 32 + qd * 8;
      const f16* apl = (const f16*)p_lo + (size_t)slot_w * SLOT + (size_t)c * 32768 +
                       lr * 32 + qd * 8;
      bool early = __all((int)(pf_seen >= (unsigned)(s + 1)));
      f16x8 Ap[16][2];
      if (early) {
#pragma unroll
        for (int kt = 0; kt < 16; ++kt) {
          Ap[kt][0] = *(const f16x8*)(aph + kt * 2048);
          Ap[kt][1] = *(const f16x8*)(apl + kt * 2048);
        }
      }
      f32x4 acc[4], accL[4];
#pragma unroll
      for (int t4 = 0; t4 < 4; ++t4) {
        acc[t4] = (f32x4){0.f,0.f,0.f,0.f};
        accL[t4] = (f32x4){0.f,0.f,0.f,0.f};
      }
      // phase 1: q_{s-1} @ Wh1
#pragma unroll
      for (int kt = 0; kt < 16; ++kt) {
#pragma unroll
        for (int t4 = 0; t4 < 4; ++t4) {
          f16x8 bw = wh_[(t4 * 16 + kt) * 64 + ln];
          acc[t4]  = __builtin_amdgcn_mfma_f32_16x16x32_f16(Aq[kt][0], bw, acc[t4], 0, 0, 0);
          accL[t4] = __builtin_amdgcn_mfma_f32_16x16x32_f16(Aq[kt][1], bw, accL[t4], 0, 0, 0);
        }
      }
      if (!early) {
        pf_seen = pollr(pfc + (ln & 15), (unsigned)(s + 1));
#pragma unroll
        for (int kt = 0; kt < 16; ++kt) {
          Ap[kt][0] = *(const f16x8*)(aph + kt * 2048);
          Ap[kt][1] = *(const f16x8*)(apl + kt * 2048);
        }
      }
      // phase 2: p_s @ Wx1
#pragma unroll
      for (int kt = 0; kt < 16; ++kt) {
#pragma unroll
        for (int t4 = 0; t4 < 4; ++t4) {
          f16x8 bw = wx_[(t4 * 16 + kt) * 64 + ln];
          acc[t4]  = __builtin_amdgcn_mfma_f32_16x16x32_f16(Ap[kt][0], bw, acc[t4], 0, 0, 0);
          accL[t4] = __builtin_amdgcn_mfma_f32_16x16x32_f16(Ap[kt][1], bw, accL[t4], 0, 0, 0);
        }
      }
      // ---- epilogue -> LDS stage ----
      float po[4];
#pragma unroll
      for (int e = 0; e < 4; ++e) {
        po[e] = 0.0f;
#pragma unroll
        for (int nh = 0; nh < 2; ++nh) {
          float v0 = acc[nh*2+0][e] + accL[nh*2+0][e] * LO + b1c0[nh];   // i / f
          float v1 = acc[nh*2+1][e] + accL[nh*2+1][e] * LO + b1c1[nh];   // g / o
          float w0 = __shfl_xor(v0, 8, 16);
          float w1 = __shfl_xor(v1, 8, 16);
          float gi = hiH ? v0 : w0;
          float gf = hiH ? w0 : v0;
          float gg = hiH ? v1 : w1;
          float go = hiH ? w1 : v1;
          float ii = sigm(gi), ff = sigm(gf), tg = tanhx(gg), oo = sigm(go);
          cst[nh][e] = ff * cst[nh][e] + ii * tg;
          float h = oo * tanhx(cst[nh][e]);
          int su = (wv * 16 + qd * 4 + e) * 16 + nh * 8 + u;
          if (hiH) {
            sh[su] = (f16)h;
          } else {
            f16 hh = (f16)h;
            slo[su] = (f16)((h - (float)hh) * 1024.0f);
          }
          po[e] += hiH ? wfv[nh] * h : 0.0f;
        }
      }
      __syncthreads();
      // ---- coop store: 2 x 2KB contiguous, 8B/lane, full-line coverage ----
      {
        unsigned short* bhq = q_hi + (size_t)slot_w * SLOT + (size_t)c * 32768 + (size_t)sl * 1024;
        unsigned short* blq = q_lo + (size_t)slot_w * SLOT + (size_t)c * 32768 + (size_t)sl * 1024;
#pragma unroll
        for (int i = tid; i < 512; i += 256) {
          int strm = i >> 8, pc = i & 255;               // 8B piece index
          const f16* src = (strm ? slo : sh) + pc * 4;
          st8((strm ? blq : bhq) + pc * 4, *(const u64*)src);
        }
      }
      __syncthreads();   // stores drained at LLC
      if (tid < 4)       // store all 4 replicas (512B apart)
        stf(qf + tid * 128 + c * 32 + sl, (unsigned)(s + 1));
      // deferred head-output reduce + atomic (off the q->q critical path)
#pragma unroll
      for (int e = 0; e < 4; ++e) {
        float r = po[e];
#pragma unroll
        for (int m = 1; m < 16; m <<= 1) r += __shfl_xor(r, m, 16);
        if (cl == 0)
          atomicAdd(part8 + (size_t)(sl & 7) * (NB * NT_) +
                        (size_t)(c * 64 + wv * 16 + qd * 4 + e) * NT_ + s, r);
      }
    }
  }
}

// ---------------------------------------------------------------------------
extern "C" void kernel_launch(void* const* d_in, const int* in_sizes, int n_in,
                              void* d_out, int out_size, void* d_ws, size_t ws_size,
                              hipStream_t stream) {
  (void)in_sizes; (void)n_in; (void)out_size; (void)ws_size;
  const float* inp = (const float*)d_in[0];
  const float* Wx0 = (const float*)d_in[1];
  const float* Wh0 = (const float*)d_in[2];
  const float* b0  = (const float*)d_in[3];
  const float* Wx1 = (const float*)d_in[4];
  const float* Wh1 = (const float*)d_in[5];
  const float* b1  = (const float*)d_in[6];
  const float* Wf  = (const float*)d_in[7];
  const float* bf  = (const float*)d_in[8];

  const size_t MB = 1u << 20;
  const size_t OFF_W    = 0;                 // 6 MiB tiled fp16 weights
  const size_t OFF_XT   = 6 * MB;            // 1 MiB
  const size_t OFF_PHI  = 7 * MB;            // 4 MiB (RING x 256 KB)
  const size_t OFF_PLO  = 11 * MB;
  const size_t OFF_QHI  = 15 * MB;
  const size_t OFF_QLO  = 19 * MB;
  const size_t OFF_PART = 23 * MB;           // 8 MiB
  const size_t OFF_CTR  = 31 * MB;           // flags: pf 2KB + qf 2KB (4 reps)

  char* ws = (char*)d_ws;
  f16* wsl = (f16*)(ws + OFF_W);
  float* xT = (float*)(ws + OFF_XT);
  unsigned short* phi = (unsigned short*)(ws + OFF_PHI);
  unsigned short* plo = (unsigned short*)(ws + OFF_PLO);
  unsigned short* qhi = (unsigned short*)(ws + OFF_QHI);
  unsigned short* qlo = (unsigned short*)(ws + OFF_QLO);
  float* part8 = (float*)(ws + OFF_PART);
  unsigned int* pfl = (unsigned int*)(ws + OFF_CTR);
  unsigned int* qfl = pfl + 512;             // pf 4x128 u32, then qf 4x128
  float* out = (float*)d_out;

  (void)hipFuncSetAttribute((const void*)lstm_main,
                            hipFuncAttributeMaxDynamicSharedMemorySize, 139264);

  // zero rings + partials + flags (contiguous; flags now 4 KB)
  (void)hipMemsetAsync(ws + OFF_PHI, 0, (OFF_CTR + 4096) - OFF_PHI, stream);

  prep_xT<<<1024, 256, 0, stream>>>(inp, xT);
  prep_w<<<12288, 256, 0, stream>>>(Wh0, Wx1, Wh1, wsl);

  lstm_main<<<256, 256, 139264, stream>>>(xT, wsl, Wx0, b0, b1, Wf,
                                          phi, plo, qhi, qlo, pfl, qfl, part8);

  reduce_out<<<1024, 256, 0, stream>>>(part8, bf, out);
}